// Round 1
// baseline (549.595 us; speedup 1.0000x reference)
//
#include <hip/hip_runtime.h>
#include <cstdint>

#define T_TOK 8192
#define Dm 1024
#define Fm 2048
#define Em 8

typedef unsigned short u16;
typedef __attribute__((ext_vector_type(8))) short short8;   // 8 bf16 (4 VGPRs)
typedef __attribute__((ext_vector_type(4))) float floatx4;  // MFMA C/D

__device__ __forceinline__ u16 f2bf(float f) {
  union { float f; unsigned u; } v; v.f = f;
  unsigned r = v.u + 0x7fffu + ((v.u >> 16) & 1u);  // RNE
  return (u16)(r >> 16);
}

__device__ __forceinline__ void gld_lds16(const void* g, void* l) {
  __builtin_amdgcn_global_load_lds(
      (const __attribute__((address_space(1))) void*)g,
      (__attribute__((address_space(3))) void*)l, 16, 0, 0);
}

// ---------------- zero metadata ----------------
__global__ void zero_meta(int* counts, int* offc, float* psum, float* zsum) {
  int t = threadIdx.x;
  if (t < 8) { counts[t] = 0; offc[t] = 0; psum[t] = 0.f; }
  if (t == 8) zsum[0] = 0.f;
}

// ---------------- prep: router (blocks 0..255) + weight transposes (blocks 256..12543) ----------------
__global__ __launch_bounds__(256) void prep_kernel(
    const float* __restrict__ Wg, const float* __restrict__ Wu, const float* __restrict__ Wd,
    u16* __restrict__ WgT, u16* __restrict__ WuT, u16* __restrict__ WdT,
    const float* __restrict__ x, const float* __restrict__ Wr, u16* __restrict__ xb,
    int* __restrict__ topi, float* __restrict__ topw,
    int* __restrict__ counts, float* __restrict__ psum, float* __restrict__ zsum) {
  __shared__ __align__(16) char smem[33056];
  int tid = threadIdx.x;
  if (blockIdx.x >= 256) {
    // ---- transpose tile ----
    u16* tile = (u16*)smem;  // 64*66 u16 = 8448B
    int bid = blockIdx.x - 256;
    int m = bid >> 9, t = bid & 511;
    int type = m >> 3, e = m & 7;
    const float* src; u16* dst; int R, C, csh;
    if (type == 0)      { src = Wg; dst = WgT; R = Dm; C = Fm; csh = 5; }
    else if (type == 1) { src = Wu; dst = WuT; R = Dm; C = Fm; csh = 5; }
    else                { src = Wd; dst = WdT; R = Fm; C = Dm; csh = 4; }
    int ty = t >> csh, tx = t & ((1 << csh) - 1);
    int r0 = ty * 64, c0 = tx * 64;
    const float* s = src + (size_t)e * R * C;
    u16* d = dst + (size_t)e * C * R;
#pragma unroll
    for (int p = 0; p < 16; ++p) {
      int idx = p * 256 + tid;
      int i = idx >> 6, j = idx & 63;
      tile[i * 66 + j] = f2bf(s[(size_t)(r0 + i) * C + (c0 + j)]);
    }
    __syncthreads();
#pragma unroll
    for (int p = 0; p < 16; ++p) {
      int idx = p * 256 + tid;
      int i = idx >> 6, j = idx & 63;
      d[(size_t)(c0 + i) * R + (r0 + j)] = tile[j * 66 + i];
    }
    return;
  }
  // ---- router block ----
  int rb = blockIdx.x;  // 0..255
  float* wr_s = (float*)smem;                        // 32768 B
  float (*redf)[9] = (float(*)[9])(smem + 32768);    // 144 B
  int (*redi)[8] = (int(*)[8])(smem + 32768 + 144);  // 128 B
  for (int i = tid; i < Dm * Em; i += 256) wr_s[i] = Wr[i];
  __syncthreads();
  int wv = tid >> 6, lane = tid & 63;
  float pl[8] = {0, 0, 0, 0, 0, 0, 0, 0};
  float zl = 0.f;
  int cl[8] = {0, 0, 0, 0, 0, 0, 0, 0};
  for (int it = 0; it < 8; ++it) {
    int t = (rb * 4 + wv) * 8 + it;
    const float* xt = x + (size_t)t * Dm;
    u16* xbt = xb + (size_t)t * Dm;
    float acc[8] = {0, 0, 0, 0, 0, 0, 0, 0};
#pragma unroll
    for (int i = 0; i < 16; ++i) {
      int dd = i * 64 + lane;
      float xv = xt[dd];
      xbt[dd] = f2bf(xv);
#pragma unroll
      for (int e2 = 0; e2 < 8; ++e2) acc[e2] += xv * wr_s[dd * 8 + e2];
    }
#pragma unroll
    for (int e2 = 0; e2 < 8; ++e2) {
      float v = acc[e2];
      for (int o = 32; o > 0; o >>= 1) v += __shfl_down(v, o);
      acc[e2] = v;
    }
    if (lane == 0) {
      float m = acc[0];
#pragma unroll
      for (int e2 = 1; e2 < 8; ++e2) m = fmaxf(m, acc[e2]);
      float p[8]; float s = 0.f;
#pragma unroll
      for (int e2 = 0; e2 < 8; ++e2) { p[e2] = expf(acc[e2] - m); s += p[e2]; }
      float inv = 1.f / s;
#pragma unroll
      for (int e2 = 0; e2 < 8; ++e2) { p[e2] *= inv; pl[e2] += p[e2]; }
      float lse = m + logf(s);
      zl += lse * lse;
      int i1 = 0;
#pragma unroll
      for (int e2 = 1; e2 < 8; ++e2) if (p[e2] > p[i1]) i1 = e2;  // strict > : low idx wins ties
      int i2 = -1; float b2 = -1e30f;
#pragma unroll
      for (int e2 = 0; e2 < 8; ++e2)
        if (e2 != i1 && p[e2] > b2) { b2 = p[e2]; i2 = e2; }
      float ssum = p[i1] + p[i2];
      topi[2 * t] = i1; topi[2 * t + 1] = i2;
      topw[2 * t] = p[i1] / ssum; topw[2 * t + 1] = p[i2] / ssum;
      cl[i1]++; cl[i2]++;
    }
  }
  if (lane == 0) {
#pragma unroll
    for (int e2 = 0; e2 < 8; ++e2) { redf[wv][e2] = pl[e2]; redi[wv][e2] = cl[e2]; }
    redf[wv][8] = zl;
  }
  __syncthreads();
  if (tid < 8) {
    atomicAdd(&psum[tid], redf[0][tid] + redf[1][tid] + redf[2][tid] + redf[3][tid]);
    atomicAdd(&counts[tid], redi[0][tid] + redi[1][tid] + redi[2][tid] + redi[3][tid]);
  } else if (tid == 8) {
    atomicAdd(zsum, redf[0][8] + redf[1][8] + redf[2][8] + redf[3][8]);
  }
}

// ---------------- scatter: compaction + global bases + aux loss ----------------
__global__ __launch_bounds__(256) void scatter_kernel(
    const int* __restrict__ topi, const float* __restrict__ topw,
    const int* __restrict__ counts, const float* __restrict__ psum, const float* __restrict__ zsum,
    int* __restrict__ offc, int* __restrict__ etok, float* __restrict__ ew,
    int* __restrict__ slots, int* __restrict__ bases, float* __restrict__ out_aux) {
  __shared__ int lcnt[8];
  __shared__ int lbase[8];
  __shared__ int basesS[8];
  int tid = threadIdx.x;
  if (blockIdx.x == 0 && tid == 0) {
    float lb = 0.f;
    for (int e = 0; e < 8; ++e)
      lb += ((float)counts[e] / (2.f * T_TOK)) * (psum[e] / (float)T_TOK);
    lb *= 8.f;
    float z = zsum[0] / (float)T_TOK;
    *out_aux = 0.01f * lb + 0.001f * z;
  }
  if (tid < 8) {
    lcnt[tid] = 0;
    int b = 0;
    for (int e = 0; e < tid; ++e) b += counts[e];
    basesS[tid] = b;
    if (blockIdx.x == 0) bases[tid] = b;
  }
  __syncthreads();
  int t = blockIdx.x * 256 + tid;
  int e0 = topi[2 * t], e1 = topi[2 * t + 1];
  int lp0 = atomicAdd(&lcnt[e0], 1);
  int lp1 = atomicAdd(&lcnt[e1], 1);
  __syncthreads();
  if (tid < 8) lbase[tid] = atomicAdd(&offc[tid], lcnt[tid]);
  __syncthreads();
  int p0 = basesS[e0] + lbase[e0] + lp0;
  etok[p0] = t; ew[p0] = topw[2 * t]; slots[2 * t] = p0;
  int p1 = basesS[e1] + lbase[e1] + lp1;
  etok[p1] = t; ew[p1] = topw[2 * t + 1]; slots[2 * t + 1] = p1;
}

// ---------------- GEMM1: 256Mx128N dual-B (g,u), BK=32, 4-ring pipelined ----------------
// 512 thr = 8 waves (2M x 4N), wave tile 128x32 on BOTH g and u -> accg[8][2]+accu[8][2] = 128 acc regs.
// LDS ring: 4 bufs x (A[256][32] + Bg[128][32] + Bu[128][32]) u16 = 4 x 32KB = 128KB, 1 block/CU.
// Group t reads buf[t%4], stages tile t+3 into buf[(t+3)%4] (holds tile t-1: dead since prev barrier)
// -> no intra-group barriers; one raw s_barrier + counted s_waitcnt vmcnt(8) per tile (never 0 in steady state).
__global__ __launch_bounds__(512, 2) void gemm1_kernel(
    const u16* __restrict__ xb, const u16* __restrict__ WgT, const u16* __restrict__ WuT,
    u16* __restrict__ h, const int* __restrict__ etok,
    const int* __restrict__ counts, const int* __restrict__ bases) {
  const int e = blockIdx.z;
  const int Ne = counts[e];
  const int m0 = blockIdx.y * 256;
  if (m0 >= Ne) return;
  const int n0 = blockIdx.x * 128;
  const int be = bases[e];

  __shared__ __align__(16) u16 lds[4 * 16384];  // 128KB

  const int tid = threadIdx.x;
  const int lane = tid & 63, wv = tid >> 6;
  const int wm = wv >> 2, wn = wv & 3;          // 2M x 4N
  const int col = lane & 15, quad = lane >> 4;

  const int srow = tid >> 2;                    // 0..127
  const int cg = (tid & 3) ^ ((srow >> 2) & 3); // swizzled k-chunk (2-way max per 16-lane quarter)
  const int ldst = tid * 8;                     // linear LDS dest (lane*16B within wave)

  const u16* wg_e = WgT + (size_t)e * Fm * Dm;  // [F][D], k-contig
  const u16* wu_e = WuT + (size_t)e * Fm * Dm;

  const u16* ag[2];
#pragma unroll
  for (int j = 0; j < 2; ++j) {
    int row = m0 + j * 128 + srow;
    int rr = row < Ne ? row : Ne - 1;
    ag[j] = xb + (size_t)etok[be + rr] * Dm + cg * 8;
  }
  const u16* bgp = wg_e + (size_t)(n0 + srow) * Dm + cg * 8;
  const u16* bup = wu_e + (size_t)(n0 + srow) * Dm + cg * 8;

  floatx4 accg[8][2], accu[8][2];
#pragma unroll
  for (int mi = 0; mi < 8; ++mi)
#pragma unroll
    for (int ni = 0; ni < 2; ++ni) { accg[mi][ni] = (floatx4)0.f; accu[mi][ni] = (floatx4)0.f; }

#define G1_STAGE_A(t) { u16* b_ = &lds[((t) & 3) * 16384]; int k0_ = (t) * 32; \
    gld_lds16(ag[0] + k0_, b_ + ldst); gld_lds16(ag[1] + k0_, b_ + 4096 + ldst); }
#define G1_STAGE_B(t) { u16* b_ = &lds[((t) & 3) * 16384]; int k0_ = (t) * 32; \
    gld_lds16(bgp + k0_, b_ + 8192 + ldst); gld_lds16(bup + k0_, b_ + 12288 + ldst); }

  G1_STAGE_A(0); G1_STAGE_B(0);
  G1_STAGE_A(1); G1_STAGE_B(1);
  G1_STAGE_A(2); G1_STAGE_B(2);
  asm volatile("s_waitcnt vmcnt(8)" ::: "memory");  // tile 0 landed (tiles 1,2 in flight)
  __builtin_amdgcn_s_barrier();
  asm volatile("" ::: "memory");
  __builtin_amdgcn_sched_barrier(0);

  for (int t = 0; t < 32; ++t) {
    const u16* Ab = &lds[(t & 3) * 16384];
    const u16* Gb = Ab + 8192;
    const u16* Ub = Ab + 12288;
    short8 bgf[2], buf_[2], af[4];
#pragma unroll
    for (int ni = 0; ni < 2; ++ni) {
      int row = wn * 32 + ni * 16 + col;
      int o = row * 32 + (((quad ^ (row >> 2)) & 3) << 3);
      bgf[ni] = *(const short8*)&Gb[o];
      buf_[ni] = *(const short8*)&Ub[o];
    }
#pragma unroll
    for (int mi = 0; mi < 4; ++mi) {
      int row = wm * 128 + mi * 16 + col;
      af[mi] = *(const short8*)&Ab[row * 32 + (((quad ^ (row >> 2)) & 3) << 3)];
    }
    if (t + 3 < 32) G1_STAGE_A(t + 3);
    __builtin_amdgcn_s_setprio(1);
#pragma unroll
    for (int mi = 0; mi < 4; ++mi)
#pragma unroll
      for (int ni = 0; ni < 2; ++ni) {
        accg[mi][ni] = __builtin_amdgcn_mfma_f32_16x16x32_bf16(af[mi], bgf[ni], accg[mi][ni], 0, 0, 0);
        accu[mi][ni] = __builtin_amdgcn_mfma_f32_16x16x32_bf16(af[mi], buf_[ni], accu[mi][ni], 0, 0, 0);
      }
    __builtin_amdgcn_s_setprio(0);
#pragma unroll
    for (int mi = 0; mi < 4; ++mi) {
      int row = wm * 128 + (mi + 4) * 16 + col;
      af[mi] = *(const short8*)&Ab[row * 32 + (((quad ^ (row >> 2)) & 3) << 3)];
    }
    if (t + 3 < 32) G1_STAGE_B(t + 3);
    __builtin_amdgcn_s_setprio(1);
#pragma unroll
    for (int mi = 0; mi < 4; ++mi)
#pragma unroll
      for (int ni = 0; ni < 2; ++ni) {
        accg[mi + 4][ni] = __builtin_amdgcn_mfma_f32_16x16x32_bf16(af[mi], bgf[ni], accg[mi + 4][ni], 0, 0, 0);
        accu[mi + 4][ni] = __builtin_amdgcn_mfma_f32_16x16x32_bf16(af[mi], buf_[ni], accu[mi + 4][ni], 0, 0, 0);
      }
    __builtin_amdgcn_s_setprio(0);
    if (t + 3 < 32)      { asm volatile("s_waitcnt vmcnt(8)" ::: "memory"); }
    else if (t + 2 < 32) { asm volatile("s_waitcnt vmcnt(4)" ::: "memory"); }
    else if (t + 1 < 32) { asm volatile("s_waitcnt vmcnt(0)" ::: "memory"); }
    if (t + 1 < 32) {
      __builtin_amdgcn_s_barrier();
      asm volatile("" ::: "memory");
      __builtin_amdgcn_sched_barrier(0);
    }
  }
#undef G1_STAGE_A
#undef G1_STAGE_B

#pragma unroll
  for (int mi = 0; mi < 8; ++mi)
#pragma unroll
    for (int ni = 0; ni < 2; ++ni) {
      int f = n0 + wn * 32 + ni * 16 + col;
#pragma unroll
      for (int r = 0; r < 4; ++r) {
        int lrow = wm * 128 + mi * 16 + quad * 4 + r;
        if (m0 + lrow < Ne) {
          float gv = accg[mi][ni][r];
          float hv = (gv / (1.f + expf(-gv))) * accu[mi][ni][r];
          h[(size_t)(be + m0 + lrow) * Fm + f] = f2bf(hv);
        }
      }
    }
}

// ---------------- GEMM2: 256Mx256N, BK=32, 4-ring pipelined, h2[slot] = w * (h @ Wd) ----------------
// 512 thr = 8 waves (2M x 4N), wave tile 128x64 -> acc[8][4] = 128 acc regs (m201 geometry).
// LDS ring: 4 bufs x (A[256][32] + B[256][32]) u16 = 128KB.
__global__ __launch_bounds__(512, 2) void gemm2_kernel(
    const u16* __restrict__ h, const u16* __restrict__ WdT, float* __restrict__ h2,
    const float* __restrict__ ew,
    const int* __restrict__ counts, const int* __restrict__ bases) {
  const int e = blockIdx.z;
  const int Ne = counts[e];
  const int m0 = blockIdx.y * 256;
  if (m0 >= Ne) return;
  const int n0 = blockIdx.x * 256;
  const int be = bases[e];

  __shared__ __align__(16) u16 lds[4 * 16384];  // 128KB
  __shared__ float wS[256];

  const int tid = threadIdx.x;
  if (tid < 256) {
    int rr = m0 + tid; rr = rr < Ne ? rr : Ne - 1;
    wS[tid] = ew[be + rr];
  }
  const int lane = tid & 63, wv = tid >> 6;
  const int wm = wv >> 2, wn = wv & 3;          // 2M x 4N
  const int col = lane & 15, quad = lane >> 4;

  const int srow = tid >> 2;                    // 0..127
  const int cg = (tid & 3) ^ ((srow >> 2) & 3);
  const int ldst = tid * 8;

  const u16* wd_e = WdT + (size_t)e * Dm * Fm;  // [D][F], k-contig

  const u16* ap[2]; const u16* bp[2];
#pragma unroll
  for (int j = 0; j < 2; ++j) {
    int row = m0 + j * 128 + srow;
    int rr = row < Ne ? row : Ne - 1;
    ap[j] = h + (size_t)(be + rr) * Fm + cg * 8;
    bp[j] = wd_e + (size_t)(n0 + j * 128 + srow) * Fm + cg * 8;
  }

  floatx4 acc[8][4];
#pragma unroll
  for (int mi = 0; mi < 8; ++mi)
#pragma unroll
    for (int ni = 0; ni < 4; ++ni) acc[mi][ni] = (floatx4)0.f;

#define G2_STAGE_A(t) { u16* b_ = &lds[((t) & 3) * 16384]; int k0_ = (t) * 32; \
    gld_lds16(ap[0] + k0_, b_ + ldst); gld_lds16(ap[1] + k0_, b_ + 4096 + ldst); }
#define G2_STAGE_B(t) { u16* b_ = &lds[((t) & 3) * 16384]; int k0_ = (t) * 32; \
    gld_lds16(bp[0] + k0_, b_ + 8192 + ldst); gld_lds16(bp[1] + k0_, b_ + 12288 + ldst); }

  G2_STAGE_A(0); G2_STAGE_B(0);
  G2_STAGE_A(1); G2_STAGE_B(1);
  G2_STAGE_A(2); G2_STAGE_B(2);
  asm volatile("s_waitcnt vmcnt(8)" ::: "memory");
  __builtin_amdgcn_s_barrier();
  asm volatile("" ::: "memory");
  __builtin_amdgcn_sched_barrier(0);

  for (int t = 0; t < 64; ++t) {
    const u16* Ab = &lds[(t & 3) * 16384];
    const u16* Bb = Ab + 8192;
    short8 bf[4], af[4];
#pragma unroll
    for (int ni = 0; ni < 4; ++ni) {
      int row = wn * 64 + ni * 16 + col;
      bf[ni] = *(const short8*)&Bb[row * 32 + (((quad ^ (row >> 2)) & 3) << 3)];
    }
#pragma unroll
    for (int mi = 0; mi < 4; ++mi) {
      int row = wm * 128 + mi * 16 + col;
      af[mi] = *(const short8*)&Ab[row * 32 + (((quad ^ (row >> 2)) & 3) << 3)];
    }
    if (t + 3 < 64) G2_STAGE_A(t + 3);
    __builtin_amdgcn_s_setprio(1);
#pragma unroll
    for (int mi = 0; mi < 4; ++mi)
#pragma unroll
      for (int ni = 0; ni < 4; ++ni)
        acc[mi][ni] = __builtin_amdgcn_mfma_f32_16x16x32_bf16(af[mi], bf[ni], acc[mi][ni], 0, 0, 0);
    __builtin_amdgcn_s_setprio(0);
#pragma unroll
    for (int mi = 0; mi < 4; ++mi) {
      int row = wm * 128 + (mi + 4) * 16 + col;
      af[mi] = *(const short8*)&Ab[row * 32 + (((quad ^ (row >> 2)) & 3) << 3)];
    }
    if (t + 3 < 64) G2_STAGE_B(t + 3);
    __builtin_amdgcn_s_setprio(1);
#pragma unroll
    for (int mi = 0; mi < 4; ++mi)
#pragma unroll
      for (int ni = 0; ni < 4; ++ni)
        acc[mi + 4][ni] = __builtin_amdgcn_mfma_f32_16x16x32_bf16(af[mi], bf[ni], acc[mi + 4][ni], 0, 0, 0);
    __builtin_amdgcn_s_setprio(0);
    if (t + 3 < 64)      { asm volatile("s_waitcnt vmcnt(8)" ::: "memory"); }
    else if (t + 2 < 64) { asm volatile("s_waitcnt vmcnt(4)" ::: "memory"); }
    else if (t + 1 < 64) { asm volatile("s_waitcnt vmcnt(0)" ::: "memory"); }
    if (t + 1 < 64) {
      __builtin_amdgcn_s_barrier();
      asm volatile("" ::: "memory");
      __builtin_amdgcn_sched_barrier(0);
    }
  }
#undef G2_STAGE_A
#undef G2_STAGE_B

#pragma unroll
  for (int mi = 0; mi < 8; ++mi)
#pragma unroll
    for (int ni = 0; ni < 4; ++ni) {
      int oc = n0 + wn * 64 + ni * 16 + col;
#pragma unroll
      for (int r = 0; r < 4; ++r) {
        int lrow = wm * 128 + mi * 16 + quad * 4 + r;
        if (m0 + lrow < Ne)
          h2[(size_t)(be + m0 + lrow) * Dm + oc] = acc[mi][ni][r] * wS[lrow];
      }
    }
}

// ---------------- combine: out[t] = h2[slot0[t]] + h2[slot1[t]] ----------------
__global__ __launch_bounds__(256) void combine_kernel(
    const float* __restrict__ h2, const int* __restrict__ slots, float* __restrict__ out) {
  int t = blockIdx.x;
  int d4 = threadIdx.x;
  int s0 = slots[2 * t], s1 = slots[2 * t + 1];
  const float4* r0 = (const float4*)(h2 + (size_t)s0 * Dm);
  const float4* r1 = (const float4*)(h2 + (size_t)s1 * Dm);
  float4 a = r0[d4], b = r1[d4];
  float4 o = make_float4(a.x + b.x, a.y + b.y, a.z + b.z, a.w + b.w);
  ((float4*)(out + (size_t)t * Dm))[d4] = o;
}

extern "C" void kernel_launch(void* const* d_in, const int* in_sizes, int n_in,
                              void* d_out, int out_size, void* d_ws, size_t ws_size,
                              hipStream_t stream) {
  const float* x = (const float*)d_in[0];
  const float* Wr = (const float*)d_in[1];
  const float* Wg = (const float*)d_in[2];
  const float* Wu = (const float*)d_in[3];
  const float* Wd = (const float*)d_in[4];
  float* out = (float*)d_out;

  char* p = (char*)d_ws;
  auto take = [&](size_t bytes) { char* r = p; p += (bytes + 255) & ~(size_t)255; return r; };
  u16* WgT = (u16*)take((size_t)Em * Fm * Dm * 2);   // 33.5 MB  } h2 (67.1 MB fp32) aliases
  u16* WuT = (u16*)take((size_t)Em * Fm * Dm * 2);   // 33.5 MB  } these two after gemm1
  u16* WdT = (u16*)take((size_t)Em * Dm * Fm * 2);
  u16* xb = (u16*)take((size_t)T_TOK * Dm * 2);
  u16* gh = (u16*)take((size_t)2 * T_TOK * Fm * 2);
  int* topi = (int*)take((size_t)T_TOK * 2 * 4);
  float* topw = (float*)take((size_t)T_TOK * 2 * 4);
  int* etok = (int*)take((size_t)2 * T_TOK * 4);
  float* ew = (float*)take((size_t)2 * T_TOK * 4);
  int* slots = (int*)take((size_t)2 * T_TOK * 4);
  int* counts = (int*)take(64);
  int* bases = (int*)take(64);
  int* offc = (int*)take(64);
  float* psum = (float*)take(64);
  float* zsum = (float*)take(64);
  float* h2 = (float*)WgT;  // alias: WgT+WuT dead after gemm1; 2*T*D*4 == 2*(E*F*D*2)

  zero_meta<<<1, 64, 0, stream>>>(counts, offc, psum, zsum);
  prep_kernel<<<dim3(24 * 512 + 256), 256, 0, stream>>>(
      Wg, Wu, Wd, WgT, WuT, WdT, x, Wr, xb, topi, topw, counts, psum, zsum);
  scatter_kernel<<<dim3(T_TOK / 256), 256, 0, stream>>>(
      topi, topw, counts, psum, zsum, offc, etok, ew, slots, bases, out + (size_t)T_TOK * Dm);
  gemm1_kernel<<<dim3(Fm / 128, 32, Em), 512, 0, stream>>>(xb, WgT, WuT, gh, etok, counts, bases);
  gemm2_kernel<<<dim3(Dm / 256, 32, Em), 512, 0, stream>>>(gh, WdT, h2, ew, counts, bases);
  combine_kernel<<<dim3(T_TOK), 256, 0, stream>>>(h2, slots, out);
}

// Round 2
// 535.911 us; speedup vs baseline: 1.0255x; 1.0255x over previous
//
#include <hip/hip_runtime.h>
#include <cstdint>

#define T_TOK 8192
#define Dm 1024
#define Fm 2048
#define Em 8

typedef unsigned short u16;
typedef __attribute__((ext_vector_type(8))) short short8;   // 8 bf16 (4 VGPRs)
typedef __attribute__((ext_vector_type(4))) float floatx4;  // MFMA C/D

__device__ __forceinline__ u16 f2bf(float f) {
  union { float f; unsigned u; } v; v.f = f;
  unsigned r = v.u + 0x7fffu + ((v.u >> 16) & 1u);  // RNE
  return (u16)(r >> 16);
}

__device__ __forceinline__ void gld_lds16(const void* g, void* l) {
  __builtin_amdgcn_global_load_lds(
      (const __attribute__((address_space(1))) void*)g,
      (__attribute__((address_space(3))) void*)l, 16, 0, 0);
}

// ---------------- zero metadata ----------------
__global__ void zero_meta(int* counts, int* offc, float* psum, float* zsum) {
  int t = threadIdx.x;
  if (t < 8) { counts[t] = 0; offc[t] = 0; psum[t] = 0.f; }
  if (t == 8) zsum[0] = 0.f;
}

// ---------------- prep: router (blocks 0..255) + weight transposes (blocks 256..12543) ----------------
__global__ __launch_bounds__(256) void prep_kernel(
    const float* __restrict__ Wg, const float* __restrict__ Wu, const float* __restrict__ Wd,
    u16* __restrict__ WgT, u16* __restrict__ WuT, u16* __restrict__ WdT,
    const float* __restrict__ x, const float* __restrict__ Wr, u16* __restrict__ xb,
    int* __restrict__ topi, float* __restrict__ topw,
    int* __restrict__ counts, float* __restrict__ psum, float* __restrict__ zsum) {
  __shared__ __align__(16) char smem[33056];
  int tid = threadIdx.x;
  if (blockIdx.x >= 256) {
    // ---- transpose tile ----
    u16* tile = (u16*)smem;  // 64*66 u16 = 8448B
    int bid = blockIdx.x - 256;
    int m = bid >> 9, t = bid & 511;
    int type = m >> 3, e = m & 7;
    const float* src; u16* dst; int R, C, csh;
    if (type == 0)      { src = Wg; dst = WgT; R = Dm; C = Fm; csh = 5; }
    else if (type == 1) { src = Wu; dst = WuT; R = Dm; C = Fm; csh = 5; }
    else                { src = Wd; dst = WdT; R = Fm; C = Dm; csh = 4; }
    int ty = t >> csh, tx = t & ((1 << csh) - 1);
    int r0 = ty * 64, c0 = tx * 64;
    const float* s = src + (size_t)e * R * C;
    u16* d = dst + (size_t)e * C * R;
#pragma unroll
    for (int p = 0; p < 16; ++p) {
      int idx = p * 256 + tid;
      int i = idx >> 6, j = idx & 63;
      tile[i * 66 + j] = f2bf(s[(size_t)(r0 + i) * C + (c0 + j)]);
    }
    __syncthreads();
#pragma unroll
    for (int p = 0; p < 16; ++p) {
      int idx = p * 256 + tid;
      int i = idx >> 6, j = idx & 63;
      d[(size_t)(c0 + i) * R + (r0 + j)] = tile[j * 66 + i];
    }
    return;
  }
  // ---- router block ----
  int rb = blockIdx.x;  // 0..255
  float* wr_s = (float*)smem;                        // 32768 B
  float (*redf)[9] = (float(*)[9])(smem + 32768);    // 144 B
  int (*redi)[8] = (int(*)[8])(smem + 32768 + 144);  // 128 B
  for (int i = tid; i < Dm * Em; i += 256) wr_s[i] = Wr[i];
  __syncthreads();
  int wv = tid >> 6, lane = tid & 63;
  float pl[8] = {0, 0, 0, 0, 0, 0, 0, 0};
  float zl = 0.f;
  int cl[8] = {0, 0, 0, 0, 0, 0, 0, 0};
  for (int it = 0; it < 8; ++it) {
    int t = (rb * 4 + wv) * 8 + it;
    const float* xt = x + (size_t)t * Dm;
    u16* xbt = xb + (size_t)t * Dm;
    float acc[8] = {0, 0, 0, 0, 0, 0, 0, 0};
#pragma unroll
    for (int i = 0; i < 16; ++i) {
      int dd = i * 64 + lane;
      float xv = xt[dd];
      xbt[dd] = f2bf(xv);
#pragma unroll
      for (int e2 = 0; e2 < 8; ++e2) acc[e2] += xv * wr_s[dd * 8 + e2];
    }
#pragma unroll
    for (int e2 = 0; e2 < 8; ++e2) {
      float v = acc[e2];
      for (int o = 32; o > 0; o >>= 1) v += __shfl_down(v, o);
      acc[e2] = v;
    }
    if (lane == 0) {
      float m = acc[0];
#pragma unroll
      for (int e2 = 1; e2 < 8; ++e2) m = fmaxf(m, acc[e2]);
      float p[8]; float s = 0.f;
#pragma unroll
      for (int e2 = 0; e2 < 8; ++e2) { p[e2] = expf(acc[e2] - m); s += p[e2]; }
      float inv = 1.f / s;
#pragma unroll
      for (int e2 = 0; e2 < 8; ++e2) { p[e2] *= inv; pl[e2] += p[e2]; }
      float lse = m + logf(s);
      zl += lse * lse;
      int i1 = 0;
#pragma unroll
      for (int e2 = 1; e2 < 8; ++e2) if (p[e2] > p[i1]) i1 = e2;  // strict > : low idx wins ties
      int i2 = -1; float b2 = -1e30f;
#pragma unroll
      for (int e2 = 0; e2 < 8; ++e2)
        if (e2 != i1 && p[e2] > b2) { b2 = p[e2]; i2 = e2; }
      float ssum = p[i1] + p[i2];
      topi[2 * t] = i1; topi[2 * t + 1] = i2;
      topw[2 * t] = p[i1] / ssum; topw[2 * t + 1] = p[i2] / ssum;
      cl[i1]++; cl[i2]++;
    }
  }
  if (lane == 0) {
#pragma unroll
    for (int e2 = 0; e2 < 8; ++e2) { redf[wv][e2] = pl[e2]; redi[wv][e2] = cl[e2]; }
    redf[wv][8] = zl;
  }
  __syncthreads();
  if (tid < 8) {
    atomicAdd(&psum[tid], redf[0][tid] + redf[1][tid] + redf[2][tid] + redf[3][tid]);
    atomicAdd(&counts[tid], redi[0][tid] + redi[1][tid] + redi[2][tid] + redi[3][tid]);
  } else if (tid == 8) {
    atomicAdd(zsum, redf[0][8] + redf[1][8] + redf[2][8] + redf[3][8]);
  }
}

// ---------------- scatter: compaction + global bases + aux loss ----------------
__global__ __launch_bounds__(256) void scatter_kernel(
    const int* __restrict__ topi, const float* __restrict__ topw,
    const int* __restrict__ counts, const float* __restrict__ psum, const float* __restrict__ zsum,
    int* __restrict__ offc, int* __restrict__ etok, float* __restrict__ ew,
    int* __restrict__ slots, int* __restrict__ bases, float* __restrict__ out_aux) {
  __shared__ int lcnt[8];
  __shared__ int lbase[8];
  __shared__ int basesS[8];
  int tid = threadIdx.x;
  if (blockIdx.x == 0 && tid == 0) {
    float lb = 0.f;
    for (int e = 0; e < 8; ++e)
      lb += ((float)counts[e] / (2.f * T_TOK)) * (psum[e] / (float)T_TOK);
    lb *= 8.f;
    float z = zsum[0] / (float)T_TOK;
    *out_aux = 0.01f * lb + 0.001f * z;
  }
  if (tid < 8) {
    lcnt[tid] = 0;
    int b = 0;
    for (int e = 0; e < tid; ++e) b += counts[e];
    basesS[tid] = b;
    if (blockIdx.x == 0) bases[tid] = b;
  }
  __syncthreads();
  int t = blockIdx.x * 256 + tid;
  int e0 = topi[2 * t], e1 = topi[2 * t + 1];
  int lp0 = atomicAdd(&lcnt[e0], 1);
  int lp1 = atomicAdd(&lcnt[e1], 1);
  __syncthreads();
  if (tid < 8) lbase[tid] = atomicAdd(&offc[tid], lcnt[tid]);
  __syncthreads();
  int p0 = basesS[e0] + lbase[e0] + lp0;
  etok[p0] = t; ew[p0] = topw[2 * t]; slots[2 * t] = p0;
  int p1 = basesS[e1] + lbase[e1] + lp1;
  etok[p1] = t; ew[p1] = topw[2 * t + 1]; slots[2 * t + 1] = p1;
}

// ---------------- GEMM1: 256Mx128N dual-B (g,u), BK=32, 4-ring pipelined ----------------
// Swizzle: 64B rows -> 8-lane groups span 8 consecutive rows; even rows hit banks 0-15, odd 16-31.
// Need the 4 even rows of each group on 4 distinct 16B slots -> chunk = quad ^ ((row>>1)&3).
// (Round-1's (row>>2)&3 gave f=0,0,1,1 on rows {0,2,4,6} -> 1.34e7 conflicts, MfmaUtil 31%.)
__global__ __launch_bounds__(512, 2) void gemm1_kernel(
    const u16* __restrict__ xb, const u16* __restrict__ WgT, const u16* __restrict__ WuT,
    u16* __restrict__ h, const int* __restrict__ etok,
    const int* __restrict__ counts, const int* __restrict__ bases) {
  const int e = blockIdx.z;
  const int Ne = counts[e];
  const int m0 = blockIdx.y * 256;
  if (m0 >= Ne) return;
  const int n0 = blockIdx.x * 128;
  const int be = bases[e];

  __shared__ __align__(16) u16 lds[4 * 16384];  // 128KB

  const int tid = threadIdx.x;
  const int lane = tid & 63, wv = tid >> 6;
  const int wm = wv >> 2, wn = wv & 3;          // 2M x 4N
  const int col = lane & 15, quad = lane >> 4;

  const int srow = tid >> 2;                    // 0..127
  const int cg = (tid & 3) ^ ((srow >> 1) & 3); // inverse-swizzled global k-chunk
  const int ldst = tid * 8;                     // linear LDS dest (lane*16B within wave)

  const u16* wg_e = WgT + (size_t)e * Fm * Dm;  // [F][D], k-contig
  const u16* wu_e = WuT + (size_t)e * Fm * Dm;

  const u16* ag[2];
#pragma unroll
  for (int j = 0; j < 2; ++j) {
    int row = m0 + j * 128 + srow;
    int rr = row < Ne ? row : Ne - 1;
    ag[j] = xb + (size_t)etok[be + rr] * Dm + cg * 8;
  }
  const u16* bgp = wg_e + (size_t)(n0 + srow) * Dm + cg * 8;
  const u16* bup = wu_e + (size_t)(n0 + srow) * Dm + cg * 8;

  floatx4 accg[8][2], accu[8][2];
#pragma unroll
  for (int mi = 0; mi < 8; ++mi)
#pragma unroll
    for (int ni = 0; ni < 2; ++ni) { accg[mi][ni] = (floatx4)0.f; accu[mi][ni] = (floatx4)0.f; }

#define G1_STAGE_A(t) { u16* b_ = &lds[((t) & 3) * 16384]; int k0_ = (t) * 32; \
    gld_lds16(ag[0] + k0_, b_ + ldst); gld_lds16(ag[1] + k0_, b_ + 4096 + ldst); }
#define G1_STAGE_B(t) { u16* b_ = &lds[((t) & 3) * 16384]; int k0_ = (t) * 32; \
    gld_lds16(bgp + k0_, b_ + 8192 + ldst); gld_lds16(bup + k0_, b_ + 12288 + ldst); }

  G1_STAGE_A(0); G1_STAGE_B(0);
  G1_STAGE_A(1); G1_STAGE_B(1);
  G1_STAGE_A(2); G1_STAGE_B(2);
  asm volatile("s_waitcnt vmcnt(8)" ::: "memory");  // tile 0 landed (tiles 1,2 in flight)
  __builtin_amdgcn_s_barrier();
  asm volatile("" ::: "memory");
  __builtin_amdgcn_sched_barrier(0);

  for (int t = 0; t < 32; ++t) {
    const u16* Ab = &lds[(t & 3) * 16384];
    const u16* Gb = Ab + 8192;
    const u16* Ub = Ab + 12288;
    short8 bgf[2], buf_[2], af[4];
#pragma unroll
    for (int ni = 0; ni < 2; ++ni) {
      int row = wn * 32 + ni * 16 + col;
      int o = row * 32 + (((quad ^ (row >> 1)) & 3) << 3);
      bgf[ni] = *(const short8*)&Gb[o];
      buf_[ni] = *(const short8*)&Ub[o];
    }
#pragma unroll
    for (int mi = 0; mi < 4; ++mi) {
      int row = wm * 128 + mi * 16 + col;
      af[mi] = *(const short8*)&Ab[row * 32 + (((quad ^ (row >> 1)) & 3) << 3)];
    }
    if (t + 3 < 32) G1_STAGE_A(t + 3);
    __builtin_amdgcn_s_setprio(1);
#pragma unroll
    for (int mi = 0; mi < 4; ++mi)
#pragma unroll
      for (int ni = 0; ni < 2; ++ni) {
        accg[mi][ni] = __builtin_amdgcn_mfma_f32_16x16x32_bf16(af[mi], bgf[ni], accg[mi][ni], 0, 0, 0);
        accu[mi][ni] = __builtin_amdgcn_mfma_f32_16x16x32_bf16(af[mi], buf_[ni], accu[mi][ni], 0, 0, 0);
      }
    __builtin_amdgcn_s_setprio(0);
#pragma unroll
    for (int mi = 0; mi < 4; ++mi) {
      int row = wm * 128 + (mi + 4) * 16 + col;
      af[mi] = *(const short8*)&Ab[row * 32 + (((quad ^ (row >> 1)) & 3) << 3)];
    }
    if (t + 3 < 32) G1_STAGE_B(t + 3);
    __builtin_amdgcn_s_setprio(1);
#pragma unroll
    for (int mi = 0; mi < 4; ++mi)
#pragma unroll
      for (int ni = 0; ni < 2; ++ni) {
        accg[mi + 4][ni] = __builtin_amdgcn_mfma_f32_16x16x32_bf16(af[mi], bgf[ni], accg[mi + 4][ni], 0, 0, 0);
        accu[mi + 4][ni] = __builtin_amdgcn_mfma_f32_16x16x32_bf16(af[mi], buf_[ni], accu[mi + 4][ni], 0, 0, 0);
      }
    __builtin_amdgcn_s_setprio(0);
    if (t + 3 < 32)      { asm volatile("s_waitcnt vmcnt(8)" ::: "memory"); }
    else if (t + 2 < 32) { asm volatile("s_waitcnt vmcnt(4)" ::: "memory"); }
    else if (t + 1 < 32) { asm volatile("s_waitcnt vmcnt(0)" ::: "memory"); }
    if (t + 1 < 32) {
      __builtin_amdgcn_s_barrier();
      asm volatile("" ::: "memory");
      __builtin_amdgcn_sched_barrier(0);
    }
  }
#undef G1_STAGE_A
#undef G1_STAGE_B

#pragma unroll
  for (int mi = 0; mi < 8; ++mi)
#pragma unroll
    for (int ni = 0; ni < 2; ++ni) {
      int f = n0 + wn * 32 + ni * 16 + col;
#pragma unroll
      for (int r = 0; r < 4; ++r) {
        int lrow = wm * 128 + mi * 16 + quad * 4 + r;
        if (m0 + lrow < Ne) {
          float gv = accg[mi][ni][r];
          float hv = (gv / (1.f + expf(-gv))) * accu[mi][ni][r];
          h[(size_t)(be + m0 + lrow) * Fm + f] = f2bf(hv);
        }
      }
    }
}

// ---------------- GEMM2: 256Mx256N, BK=32, 4-ring pipelined, h2[slot] = w * (h @ Wd) ----------------
__global__ __launch_bounds__(512, 2) void gemm2_kernel(
    const u16* __restrict__ h, const u16* __restrict__ WdT, float* __restrict__ h2,
    const float* __restrict__ ew,
    const int* __restrict__ counts, const int* __restrict__ bases) {
  const int e = blockIdx.z;
  const int Ne = counts[e];
  const int m0 = blockIdx.y * 256;
  if (m0 >= Ne) return;
  const int n0 = blockIdx.x * 256;
  const int be = bases[e];

  __shared__ __align__(16) u16 lds[4 * 16384];  // 128KB
  __shared__ float wS[256];

  const int tid = threadIdx.x;
  if (tid < 256) {
    int rr = m0 + tid; rr = rr < Ne ? rr : Ne - 1;
    wS[tid] = ew[be + rr];
  }
  const int lane = tid & 63, wv = tid >> 6;
  const int wm = wv >> 2, wn = wv & 3;          // 2M x 4N
  const int col = lane & 15, quad = lane >> 4;

  const int srow = tid >> 2;                    // 0..127
  const int cg = (tid & 3) ^ ((srow >> 1) & 3);
  const int ldst = tid * 8;

  const u16* wd_e = WdT + (size_t)e * Dm * Fm;  // [D][F], k-contig

  const u16* ap[2]; const u16* bp[2];
#pragma unroll
  for (int j = 0; j < 2; ++j) {
    int row = m0 + j * 128 + srow;
    int rr = row < Ne ? row : Ne - 1;
    ap[j] = h + (size_t)(be + rr) * Fm + cg * 8;
    bp[j] = wd_e + (size_t)(n0 + j * 128 + srow) * Fm + cg * 8;
  }

  floatx4 acc[8][4];
#pragma unroll
  for (int mi = 0; mi < 8; ++mi)
#pragma unroll
    for (int ni = 0; ni < 4; ++ni) acc[mi][ni] = (floatx4)0.f;

#define G2_STAGE_A(t) { u16* b_ = &lds[((t) & 3) * 16384]; int k0_ = (t) * 32; \
    gld_lds16(ap[0] + k0_, b_ + ldst); gld_lds16(ap[1] + k0_, b_ + 4096 + ldst); }
#define G2_STAGE_B(t) { u16* b_ = &lds[((t) & 3) * 16384]; int k0_ = (t) * 32; \
    gld_lds16(bp[0] + k0_, b_ + 8192 + ldst); gld_lds16(bp[1] + k0_, b_ + 12288 + ldst); }

  G2_STAGE_A(0); G2_STAGE_B(0);
  G2_STAGE_A(1); G2_STAGE_B(1);
  G2_STAGE_A(2); G2_STAGE_B(2);
  asm volatile("s_waitcnt vmcnt(8)" ::: "memory");
  __builtin_amdgcn_s_barrier();
  asm volatile("" ::: "memory");
  __builtin_amdgcn_sched_barrier(0);

  for (int t = 0; t < 64; ++t) {
    const u16* Ab = &lds[(t & 3) * 16384];
    const u16* Bb = Ab + 8192;
    short8 bf[4], af[4];
#pragma unroll
    for (int ni = 0; ni < 4; ++ni) {
      int row = wn * 64 + ni * 16 + col;
      bf[ni] = *(const short8*)&Bb[row * 32 + (((quad ^ (row >> 1)) & 3) << 3)];
    }
#pragma unroll
    for (int mi = 0; mi < 4; ++mi) {
      int row = wm * 128 + mi * 16 + col;
      af[mi] = *(const short8*)&Ab[row * 32 + (((quad ^ (row >> 1)) & 3) << 3)];
    }
    if (t + 3 < 64) G2_STAGE_A(t + 3);
    __builtin_amdgcn_s_setprio(1);
#pragma unroll
    for (int mi = 0; mi < 4; ++mi)
#pragma unroll
      for (int ni = 0; ni < 4; ++ni)
        acc[mi][ni] = __builtin_amdgcn_mfma_f32_16x16x32_bf16(af[mi], bf[ni], acc[mi][ni], 0, 0, 0);
    __builtin_amdgcn_s_setprio(0);
#pragma unroll
    for (int mi = 0; mi < 4; ++mi) {
      int row = wm * 128 + (mi + 4) * 16 + col;
      af[mi] = *(const short8*)&Ab[row * 32 + (((quad ^ (row >> 1)) & 3) << 3)];
    }
    if (t + 3 < 64) G2_STAGE_B(t + 3);
    __builtin_amdgcn_s_setprio(1);
#pragma unroll
    for (int mi = 0; mi < 4; ++mi)
#pragma unroll
      for (int ni = 0; ni < 4; ++ni)
        acc[mi + 4][ni] = __builtin_amdgcn_mfma_f32_16x16x32_bf16(af[mi], bf[ni], acc[mi + 4][ni], 0, 0, 0);
    __builtin_amdgcn_s_setprio(0);
    if (t + 3 < 64)      { asm volatile("s_waitcnt vmcnt(8)" ::: "memory"); }
    else if (t + 2 < 64) { asm volatile("s_waitcnt vmcnt(4)" ::: "memory"); }
    else if (t + 1 < 64) { asm volatile("s_waitcnt vmcnt(0)" ::: "memory"); }
    if (t + 1 < 64) {
      __builtin_amdgcn_s_barrier();
      asm volatile("" ::: "memory");
      __builtin_amdgcn_sched_barrier(0);
    }
  }
#undef G2_STAGE_A
#undef G2_STAGE_B

#pragma unroll
  for (int mi = 0; mi < 8; ++mi)
#pragma unroll
    for (int ni = 0; ni < 4; ++ni) {
      int oc = n0 + wn * 64 + ni * 16 + col;
#pragma unroll
      for (int r = 0; r < 4; ++r) {
        int lrow = wm * 128 + mi * 16 + quad * 4 + r;
        if (m0 + lrow < Ne)
          h2[(size_t)(be + m0 + lrow) * Dm + oc] = acc[mi][ni][r] * wS[lrow];
      }
    }
}

// ---------------- combine: out[t] = h2[slot0[t]] + h2[slot1[t]] ----------------
__global__ __launch_bounds__(256) void combine_kernel(
    const float* __restrict__ h2, const int* __restrict__ slots, float* __restrict__ out) {
  int t = blockIdx.x;
  int d4 = threadIdx.x;
  int s0 = slots[2 * t], s1 = slots[2 * t + 1];
  const float4* r0 = (const float4*)(h2 + (size_t)s0 * Dm);
  const float4* r1 = (const float4*)(h2 + (size_t)s1 * Dm);
  float4 a = r0[d4], b = r1[d4];
  float4 o = make_float4(a.x + b.x, a.y + b.y, a.z + b.z, a.w + b.w);
  ((float4*)(out + (size_t)t * Dm))[d4] = o;
}

extern "C" void kernel_launch(void* const* d_in, const int* in_sizes, int n_in,
                              void* d_out, int out_size, void* d_ws, size_t ws_size,
                              hipStream_t stream) {
  const float* x = (const float*)d_in[0];
  const float* Wr = (const float*)d_in[1];
  const float* Wg = (const float*)d_in[2];
  const float* Wu = (const float*)d_in[3];
  const float* Wd = (const float*)d_in[4];
  float* out = (float*)d_out;

  char* p = (char*)d_ws;
  auto take = [&](size_t bytes) { char* r = p; p += (bytes + 255) & ~(size_t)255; return r; };
  u16* WgT = (u16*)take((size_t)Em * Fm * Dm * 2);   // 33.5 MB  } h2 (67.1 MB fp32) aliases
  u16* WuT = (u16*)take((size_t)Em * Fm * Dm * 2);   // 33.5 MB  } these two after gemm1
  u16* WdT = (u16*)take((size_t)Em * Dm * Fm * 2);
  u16* xb = (u16*)take((size_t)T_TOK * Dm * 2);
  u16* gh = (u16*)take((size_t)2 * T_TOK * Fm * 2);
  int* topi = (int*)take((size_t)T_TOK * 2 * 4);
  float* topw = (float*)take((size_t)T_TOK * 2 * 4);
  int* etok = (int*)take((size_t)2 * T_TOK * 4);
  float* ew = (float*)take((size_t)2 * T_TOK * 4);
  int* slots = (int*)take((size_t)2 * T_TOK * 4);
  int* counts = (int*)take(64);
  int* bases = (int*)take(64);
  int* offc = (int*)take(64);
  float* psum = (float*)take(64);
  float* zsum = (float*)take(64);
  float* h2 = (float*)WgT;  // alias: WgT+WuT dead after gemm1; 2*T*D*4 == 2*(E*F*D*2)

  zero_meta<<<1, 64, 0, stream>>>(counts, offc, psum, zsum);
  prep_kernel<<<dim3(24 * 512 + 256), 256, 0, stream>>>(
      Wg, Wu, Wd, WgT, WuT, WdT, x, Wr, xb, topi, topw, counts, psum, zsum);
  scatter_kernel<<<dim3(T_TOK / 256), 256, 0, stream>>>(
      topi, topw, counts, psum, zsum, offc, etok, ew, slots, bases, out + (size_t)T_TOK * Dm);
  gemm1_kernel<<<dim3(Fm / 128, 32, Em), 512, 0, stream>>>(xb, WgT, WuT, gh, etok, counts, bases);
  gemm2_kernel<<<dim3(Dm / 256, 32, Em), 512, 0, stream>>>(gh, WdT, h2, ew, counts, bases);
  combine_kernel<<<dim3(T_TOK), 256, 0, stream>>>(h2, slots, out);
}